// Round 3
// baseline (119015.845 us; speedup 1.0000x reference)
//
#include <hip/hip_runtime.h>
#include <hip/hip_cooperative_groups.h>
#include <cstdint>
#include <math.h>

namespace cg = cooperative_groups;
typedef unsigned int u32;

#define BB 256   // batch
#define NN 256   // nodes
#define EE 256   // enc dim
#define HH 512   // hidden
#define G4 2048  // 4H
#define KK 768   // E + H
#define TT 256   // steps
#define NBLK 256
#define NTHR 512

// ---------------- Threefry-2x32, exactly as jax/_src/prng.py ----------------
__device__ __forceinline__ u32 rotl(u32 x, int d) { return (x << d) | (x >> (32 - d)); }

__device__ __forceinline__ void tf4(u32& x0, u32& x1, int r0, int r1, int r2, int r3) {
  x0 += x1; x1 = rotl(x1, r0); x1 ^= x0;
  x0 += x1; x1 = rotl(x1, r1); x1 ^= x0;
  x0 += x1; x1 = rotl(x1, r2); x1 ^= x0;
  x0 += x1; x1 = rotl(x1, r3); x1 ^= x0;
}

__device__ __forceinline__ void threefry2x32(u32 k0, u32 k1, u32 x0, u32 x1, u32& o0, u32& o1) {
  u32 k2 = k0 ^ k1 ^ 0x1BD11BDAu;
  x0 += k0; x1 += k1;
  tf4(x0, x1, 13, 15, 26, 6);  x0 += k1; x1 += k2 + 1u;
  tf4(x0, x1, 17, 29, 16, 24); x0 += k2; x1 += k0 + 2u;
  tf4(x0, x1, 13, 15, 26, 6);  x0 += k0; x1 += k1 + 3u;
  tf4(x0, x1, 17, 29, 16, 24); x0 += k1; x1 += k2 + 4u;
  tf4(x0, x1, 13, 15, 26, 6);  x0 += k2; x1 += k0 + 5u;
  o0 = x0; o1 = x1;
}

struct Args {
  const float *enc, *W_ih, *W_hh, *b_ih, *b_hh, *W_q, *W_k, *v;
  float *out;
  float *kT;     // [B][H][N] f32
  float *Wc;     // [K=768][2048] f32, gate-interleaved permuted columns
  float *WqT;    // [H][H] f32 (k-major)
  double *bsum;  // [2048]
  u32 *keys;     // [256][2]
  double *q;     // [B][H]
  double *start; // [B][E]
  double *h0, *h1; // [B][H] double-buffered hidden
  double *c;     // [B][H]
  int *visited;  // [B][N]
  double *logp;  // [B]
};

__global__ __launch_bounds__(NTHR) void mono_kernel(Args a) {
  cg::grid_group gg = cg::this_grid();
  const int blk = blockIdx.x;
  const int t = threadIdx.x;
  __shared__ alignas(16) unsigned char SMRAW[33344];

  // ============ phase 0: init + weights + kenc ============
  {
    const int tid = blk * NTHR + t;
    const int tot = NBLK * NTHR;  // 131072
    if (tid < BB * EE) a.start[tid] = 0.0;
    if (tid < BB * HH) { a.h0[tid] = 0.0; a.h1[tid] = 0.0; a.c[tid] = 0.0; }
    if (tid < BB * NN) a.visited[tid] = 0;
    if (tid < BB) a.logp[tid] = 0.0;
    if (tid < 256) {
      // jax_threefry_partitionable=True: split(key(42),256)
      u32 o0, o1;
      threefry2x32(0u, 42u, 0u, (u32)tid, o0, o1);
      a.keys[2 * tid] = o0; a.keys[2 * tid + 1] = o1;
    }
    if (tid < G4) a.bsum[tid] = (double)a.b_ih[tid] + (double)a.b_hh[tid];
    for (int i = tid; i < HH * HH; i += tot) {
      int h2 = i >> 9, h = i & 511;
      a.WqT[i] = a.W_q[h * HH + h2];
    }
    // Wc permuted: col = x16*64 + g*16 + w  <->  orig gate col j' = g*512 + x16*16 + w
    for (int i = tid; i < KK * G4; i += tot) {
      int k = i >> 11, col = i & 2047;
      int x16 = col >> 6, g = (col >> 4) & 3, w = col & 15;
      int j = g * HH + x16 * 16 + w;
      a.Wc[i] = (k < EE) ? a.W_ih[j * EE + k] : a.W_hh[j * HH + (k - EE)];
    }
  }
  // kenc: kT[b][h][n] = sum_e enc[b][n][e] * W_k[h][e], fp64 acc (e ascending)
  {
    float (*encS)[65] = (float(*)[65])SMRAW;
    float (*wkS)[65]  = (float(*)[65])(SMRAW + 64 * 65 * 4);
    const int tn = t & 63, th = t >> 6;  // th = wave id, 0..7
    for (int tile = blk; tile < 8 * 4 * BB; tile += NBLK) {
      const int bx = tile & 7, by = (tile >> 3) & 3, b = tile >> 5;
      const int h0i = bx * 64, n0 = by * 64;
      double acc[8];
#pragma unroll
      for (int i = 0; i < 8; i++) acc[i] = 0.0;
      for (int ec = 0; ec < EE; ec += 64) {
        __syncthreads();
#pragma unroll
        for (int i = 0; i < 8; i++) {
          int idx = i * NTHR + t; int r = idx >> 6, cc = idx & 63;
          encS[r][cc] = a.enc[((size_t)b * NN + n0 + r) * EE + ec + cc];
          wkS[r][cc]  = a.W_k[(size_t)(h0i + r) * EE + ec + cc];
        }
        __syncthreads();
#pragma unroll 8
        for (int e = 0; e < 64; e++) {
          double ev = (double)encS[tn][e];
#pragma unroll
          for (int i = 0; i < 8; i++) acc[i] += (double)wkS[th * 8 + i][e] * ev;
        }
      }
#pragma unroll
      for (int i = 0; i < 8; i++)
        a.kT[((size_t)b * HH + h0i + th * 8 + i) * NN + n0 + tn] = (float)acc[i];
    }
  }
  __threadfence();
  gg.sync();
  __threadfence();

  // ============ decode loop ============
  for (int step = 0; step < TT; step++) {
    double* hPrev = (step & 1) ? a.h1 : a.h0;
    double* hCur  = (step & 1) ? a.h0 : a.h1;

    // ===== P1: gates GEMM (fp64) fused with LSTM =====
    {
      double (*aS)[34] = (double(*)[34])SMRAW;            // 32x34x8 = 8704
      double (*bS)[68] = (double(*)[68])(SMRAW + 8704);   // 32x68x8 = 17408
      const int tx = t & 15, ty = t >> 4;   // ty 0..31 (row), tx*4 col quad
      const int jb = blk & 31, bt = blk >> 5;
      const int b0 = bt * 32;
      double acc0, acc1, acc2, acc3;
      {
        int c0 = tx * 4;
        acc0 = a.bsum[((c0    ) >> 4) * HH + jb * 16 + ((c0    ) & 15)];
        acc1 = a.bsum[((c0 + 1) >> 4) * HH + jb * 16 + ((c0 + 1) & 15)];
        acc2 = a.bsum[((c0 + 2) >> 4) * HH + jb * 16 + ((c0 + 2) & 15)];
        acc3 = a.bsum[((c0 + 3) >> 4) * HH + jb * 16 + ((c0 + 3) & 15)];
      }
      for (int kc = 0; kc < KK; kc += 32) {
        __syncthreads();
        {
          int r = t >> 4, c = (t & 15) * 2;
          const double* asrc = (kc < EE)
              ? (a.start + (size_t)(b0 + r) * EE + kc + c)
              : (hPrev   + (size_t)(b0 + r) * HH + (kc - EE) + c);
          *(double2*)&aS[r][c] = *(const double2*)asrc;
          int c4 = (t & 15) * 4;
          float4 bv = *(const float4*)&a.Wc[(size_t)(kc + r) * G4 + jb * 64 + c4];
          bS[r][c4]     = (double)bv.x;
          bS[r][c4 + 1] = (double)bv.y;
          bS[r][c4 + 2] = (double)bv.z;
          bS[r][c4 + 3] = (double)bv.w;
        }
        __syncthreads();
#pragma unroll 8
        for (int kk = 0; kk < 32; kk++) {
          double av = aS[ty][kk];
          double2 b01 = *(const double2*)&bS[kk][tx * 4];
          double2 b23 = *(const double2*)&bS[kk][tx * 4 + 2];
          acc0 += av * b01.x;
          acc1 += av * b01.y;
          acc2 += av * b23.x;
          acc3 += av * b23.y;
        }
      }
      __syncthreads();
      double (*gS)[66] = (double(*)[66])SMRAW;  // 32x66x8 = 16896 (overlays aS/bS)
      gS[ty][tx * 4]     = acc0;
      gS[ty][tx * 4 + 1] = acc1;
      gS[ty][tx * 4 + 2] = acc2;
      gS[ty][tx * 4 + 3] = acc3;
      __syncthreads();
      {
        const int b = t >> 4, w = t & 15;
        double ig = gS[b][w], fg = gS[b][16 + w], gv = gS[b][32 + w], og = gS[b][48 + w];
        double si = 1.0 / (1.0 + exp(-ig));
        double sf = 1.0 / (1.0 + exp(-fg));
        double so = 1.0 / (1.0 + exp(-og));
        size_t ci = (size_t)(b0 + b) * HH + jb * 16 + w;
        double cn = sf * a.c[ci] + si * tanh(gv);
        a.c[ci] = cn;
        hCur[ci] = so * tanh(cn);
      }
    }
    __threadfence(); gg.sync(); __threadfence();

    // ===== P2: q = h @ WqT (fp64, k ascending) =====
    {
      double (*hS)[34] = (double(*)[34])SMRAW;            // 16x34x8 = 4352
      double (*wS)[34] = (double(*)[34])(SMRAW + 4352);   // 32x34x8 = 8704
      const int tx = t & 31, ty = t >> 5;  // ty 0..15
      const int j0 = (blk & 15) * 32, b0 = (blk >> 4) * 16;
      double acc = 0.0;
      for (int kc = 0; kc < HH; kc += 32) {
        __syncthreads();
        {
          int r = t >> 5, cc = t & 31;
          hS[r][cc] = hCur[(size_t)(b0 + r) * HH + kc + cc];
#pragma unroll
          for (int i = 0; i < 2; i++) {
            int idx = i * NTHR + t; int rr = idx >> 5, c2 = idx & 31;
            wS[rr][c2] = (double)a.WqT[(size_t)(kc + rr) * HH + j0 + c2];
          }
        }
        __syncthreads();
#pragma unroll 8
        for (int kk = 0; kk < 32; kk++) acc += hS[ty][kk] * wS[kk][tx];
      }
      a.q[(size_t)(b0 + ty) * HH + j0 + tx] = acc;
    }
    __threadfence(); gg.sync(); __threadfence();

    // ===== P3: attention + gumbel sample + softmax + state update =====
    {
      double* qS  = (double*)SMRAW;            // 512*8
      float*  vS  = (float*)(SMRAW + 4096);    // 512*4
      double* red = (double*)(SMRAW + 6144);   // 512*8
      double* sS  = (double*)(SMRAW + 10240);  // 256*8
      int*   redi = (int*)(SMRAW + 12288);     // 256*4
      int*   idxS = (int*)(SMRAW + 13312);
      const int b = blk;
      const int n = t & 255, half = t >> 8;
      qS[t] = a.q[(size_t)b * HH + t];
      vS[t] = a.v[t];
      __syncthreads();

      const float* kp = a.kT + ((size_t)b * HH + half * 256) * NN + n;
      double a0 = 0.0, a1 = 0.0;
#pragma unroll 4
      for (int h = 0; h < 256; h += 2) {
        float k0 = kp[(size_t)h * NN];
        float k1 = kp[(size_t)(h + 1) * NN];
        int hh = half * 256 + h;
        a0 += (double)vS[hh]     * (double)tanhf((float)(qS[hh]     + (double)k0));
        a1 += (double)vS[hh + 1] * (double)tanhf((float)(qS[hh + 1] + (double)k1));
      }
      red[t] = a0 + a1;
      __syncthreads();

      if (t < 256) {
        double s = red[t] + red[256 + t];
        if (a.visited[b * 256 + t]) s -= 1.0e6;
        sS[t] = s;
      }
      __syncthreads();

      if (t < 256) {
        u32 fl = (u32)(b * 256 + t);
        u32 o0, o1;
        threefry2x32(a.keys[2 * step], a.keys[2 * step + 1], 0u, fl, o0, o1);
        u32 bits = o0 ^ o1;
        u32 fb = (bits >> 9) | 0x3F800000u;
        float uf = __uint_as_float(fb) - 1.0f;
        double u = (uf > 0.0f) ? (double)uf : (double)1.17549435e-38f;
        double gmb = -log(-log(u));
        red[t] = gmb + sS[t];
        redi[t] = t;
      }
      __syncthreads();
      for (int s2 = 128; s2 > 0; s2 >>= 1) {
        if (t < s2) {
          double v1 = red[t], v2 = red[t + s2];
          int i1 = redi[t], i2 = redi[t + s2];
          if (v2 > v1 || (v2 == v1 && i2 < i1)) { red[t] = v2; redi[t] = i2; }
        }
        __syncthreads();
      }
      if (t == 0) *idxS = redi[0];

      if (t < 256) red[t] = sS[t];
      __syncthreads();
      for (int s2 = 128; s2 > 0; s2 >>= 1) {
        if (t < s2) red[t] = fmax(red[t], red[t + s2]);
        __syncthreads();
      }
      double m = red[0];
      __syncthreads();
      if (t < 256) red[t] = exp(sS[t] - m);
      __syncthreads();
      for (int s2 = 128; s2 > 0; s2 >>= 1) {
        if (t < s2) red[t] += red[t + s2];
        __syncthreads();
      }
      if (t == 0) {
        int bi = *idxS;
        double p = exp(sS[bi] - m) / red[0];
        a.logp[b] += p;
        a.out[(size_t)b * TT + step] = (float)bi;
        a.visited[b * 256 + bi] = 1;
      }
      __syncthreads();
      if (t < 256) a.start[(size_t)b * EE + t] = (double)a.enc[((size_t)b * NN + *idxS) * EE + t];
    }
    __threadfence(); gg.sync(); __threadfence();
  }

  if (blk == 0 && t < BB) a.out[BB * TT + t] = (float)a.logp[t];
}

// ---------------- host launch ---------------------------------------------
extern "C" void kernel_launch(void* const* d_in, const int* in_sizes, int n_in,
                              void* d_out, int out_size, void* d_ws, size_t ws_size,
                              hipStream_t stream) {
  char* ws = (char*)d_ws;
  Args a;
  a.enc  = (const float*)d_in[0];
  a.W_ih = (const float*)d_in[1];
  a.W_hh = (const float*)d_in[2];
  a.b_ih = (const float*)d_in[3];
  a.b_hh = (const float*)d_in[4];
  a.W_q  = (const float*)d_in[5];
  a.W_k  = (const float*)d_in[6];
  a.v    = (const float*)d_in[7];
  a.out  = (float*)d_out;

  a.kT      = (float*)(ws + 0);            // 134217728
  a.Wc      = (float*)(ws + 134217728);    // 6291456
  a.WqT     = (float*)(ws + 140509184);    // 1048576
  a.bsum    = (double*)(ws + 141557760);   // 16384
  a.keys    = (u32*)(ws + 141574144);      // 2048
  a.q       = (double*)(ws + 141576192);   // 1048576
  a.start   = (double*)(ws + 142624768);   // 524288
  a.h0      = (double*)(ws + 143149056);   // 1048576
  a.h1      = (double*)(ws + 144197632);   // 1048576
  a.c       = (double*)(ws + 145246208);   // 1048576
  a.visited = (int*)(ws + 146294784);      // 262144
  a.logp    = (double*)(ws + 146556928);   // 2048

  void* kargs[] = { &a };
  hipLaunchCooperativeKernel(reinterpret_cast<void*>(&mono_kernel),
                             dim3(NBLK), dim3(NTHR), kargs, 0, stream);
}

// Round 4
// 73191.901 us; speedup vs baseline: 1.6261x; 1.6261x over previous
//
#include <hip/hip_runtime.h>
#include <cstdint>
#include <math.h>

typedef unsigned int u32;

#define BB 256   // batch
#define NN 256   // nodes
#define EE 256   // enc dim
#define HH 512   // hidden
#define G4 2048  // 4H
#define KK 768   // E + H
#define TT 256   // steps
#define NBLK 256
#define NTHR 512

// ---------------- Threefry-2x32, exactly as jax/_src/prng.py ----------------
__device__ __forceinline__ u32 rotl(u32 x, int d) { return (x << d) | (x >> (32 - d)); }

__device__ __forceinline__ void tf4(u32& x0, u32& x1, int r0, int r1, int r2, int r3) {
  x0 += x1; x1 = rotl(x1, r0); x1 ^= x0;
  x0 += x1; x1 = rotl(x1, r1); x1 ^= x0;
  x0 += x1; x1 = rotl(x1, r2); x1 ^= x0;
  x0 += x1; x1 = rotl(x1, r3); x1 ^= x0;
}

__device__ __forceinline__ void threefry2x32(u32 k0, u32 k1, u32 x0, u32 x1, u32& o0, u32& o1) {
  u32 k2 = k0 ^ k1 ^ 0x1BD11BDAu;
  x0 += k0; x1 += k1;
  tf4(x0, x1, 13, 15, 26, 6);  x0 += k1; x1 += k2 + 1u;
  tf4(x0, x1, 17, 29, 16, 24); x0 += k2; x1 += k0 + 2u;
  tf4(x0, x1, 13, 15, 26, 6);  x0 += k0; x1 += k1 + 3u;
  tf4(x0, x1, 17, 29, 16, 24); x0 += k1; x1 += k2 + 4u;
  tf4(x0, x1, 13, 15, 26, 6);  x0 += k2; x1 += k0 + 5u;
  o0 = x0; o1 = x1;
}

struct Args {
  const float *enc, *W_ih, *W_hh, *b_ih, *b_hh, *W_q, *W_k, *v;
  float *out;
  float *kT;       // [B][H][N] f32
  float *Wc;       // [K=768][2048] f32, gate-interleaved permuted columns
  float *WqT;      // [H][H] f32 (k-major)
  double *bsum;    // [2048]
  u32 *keys;       // [256][2]
  double *start;   // [B][E]
  double *h0, *h1; // [B][H] double-buffered hidden
  double *c;       // [B][H]
  u32 *bar;        // [0]=cnt, [32]=gen (separate cachelines)
};

// Lean grid barrier: LLC atomic arrive + generation spin. Release/acquire via
// __threadfence() (agent scope: buffer_wbl2 + buffer_inv on gfx950).
__device__ __forceinline__ void grid_barrier(u32* cnt, u32* gen) {
  __syncthreads();  // drains this block's vmem (vmcnt 0) before the fence
  if (threadIdx.x == 0) {
    u32 g = __hip_atomic_load(gen, __ATOMIC_RELAXED, __HIP_MEMORY_SCOPE_AGENT);
    __threadfence();  // release: push block's writes to device-visible point
    if (atomicAdd(cnt, 1u) == NBLK - 1u) {
      __hip_atomic_store(cnt, 0u, __ATOMIC_RELAXED, __HIP_MEMORY_SCOPE_AGENT);
      __threadfence();
      atomicAdd(gen, 1u);
    } else {
      while (__hip_atomic_load(gen, __ATOMIC_RELAXED, __HIP_MEMORY_SCOPE_AGENT) == g) {
        __builtin_amdgcn_s_sleep(2);
      }
    }
    __threadfence();  // acquire: invalidate L1/L2 so fresh data is seen
  }
  __syncthreads();
}

__global__ __launch_bounds__(NTHR) void mono_kernel(Args a) {
  const int blk = blockIdx.x;
  const int t = threadIdx.x;
  __shared__ alignas(16) unsigned char SMRAW[33344];
  __shared__ int visS[NN];       // persistent per-block (batch = blk)
  __shared__ double logpS;
  u32* bcnt = a.bar;
  u32* bgen = a.bar + 32;

  // ============ phase 0: init + weights + kenc ============
  {
    const int tid = blk * NTHR + t;
    const int tot = NBLK * NTHR;  // 131072
    if (tid < BB * EE) a.start[tid] = 0.0;
    if (tid < BB * HH) { a.h0[tid] = 0.0; a.c[tid] = 0.0; }
    if (tid < 256) {
      // jax_threefry_partitionable=True: split(key(42),256)
      u32 o0, o1;
      threefry2x32(0u, 42u, 0u, (u32)tid, o0, o1);
      a.keys[2 * tid] = o0; a.keys[2 * tid + 1] = o1;
    }
    if (tid < G4) a.bsum[tid] = (double)a.b_ih[tid] + (double)a.b_hh[tid];
    for (int i = tid; i < HH * HH; i += tot) {
      int h2 = i >> 9, h = i & 511;
      a.WqT[i] = a.W_q[h * HH + h2];
    }
    // Wc permuted: col = x16*64 + g*16 + w  <->  orig gate col j = g*512 + x16*16 + w
    for (int i = tid; i < KK * G4; i += tot) {
      int k = i >> 11, col = i & 2047;
      int x16 = col >> 6, g = (col >> 4) & 3, w = col & 15;
      int j = g * HH + x16 * 16 + w;
      a.Wc[i] = (k < EE) ? a.W_ih[j * EE + k] : a.W_hh[j * HH + (k - EE)];
    }
    if (t < NN) visS[t] = 0;
    if (t == 0) logpS = 0.0;
  }
  // kenc: kT[b][h][n] = sum_e enc[b][n][e] * W_k[h][e], fp64 acc (e ascending)
  {
    float (*encS)[65] = (float(*)[65])SMRAW;
    float (*wkS)[65]  = (float(*)[65])(SMRAW + 64 * 65 * 4);
    const int tn = t & 63, th = t >> 6;  // th = wave id, 0..7
    for (int tile = blk; tile < 8 * 4 * BB; tile += NBLK) {
      const int bx = tile & 7, by = (tile >> 3) & 3, b = tile >> 5;
      const int h0i = bx * 64, n0 = by * 64;
      double acc[8];
#pragma unroll
      for (int i = 0; i < 8; i++) acc[i] = 0.0;
      for (int ec = 0; ec < EE; ec += 64) {
        __syncthreads();
#pragma unroll
        for (int i = 0; i < 8; i++) {
          int idx = i * NTHR + t; int r = idx >> 6, cc = idx & 63;
          encS[r][cc] = a.enc[((size_t)b * NN + n0 + r) * EE + ec + cc];
          wkS[r][cc]  = a.W_k[(size_t)(h0i + r) * EE + ec + cc];
        }
        __syncthreads();
#pragma unroll 8
        for (int e = 0; e < 64; e++) {
          double ev = (double)encS[tn][e];
#pragma unroll
          for (int i = 0; i < 8; i++) acc[i] += (double)wkS[th * 8 + i][e] * ev;
        }
      }
#pragma unroll
      for (int i = 0; i < 8; i++)
        a.kT[((size_t)b * HH + h0i + th * 8 + i) * NN + n0 + tn] = (float)acc[i];
    }
  }
  grid_barrier(bcnt, bgen);

  // ============ decode loop ============
  for (int step = 0; step < TT; step++) {
    double* hPrev = (step & 1) ? a.h1 : a.h0;
    double* hCur  = (step & 1) ? a.h0 : a.h1;

    // ===== P1: gates GEMM (fp64) fused with LSTM; block = (jb, bt) =====
    {
      double (*aS)[34] = (double(*)[34])SMRAW;            // 32x34x8 = 8704
      double (*bS)[68] = (double(*)[68])(SMRAW + 8704);   // 32x68x8 = 17408
      const int tx = t & 15, ty = t >> 4;   // ty 0..31 (row), tx*4 col quad
      const int jb = blk & 31, bt = blk >> 5;
      const int b0 = bt * 32;
      double acc0, acc1, acc2, acc3;
      {
        int c0 = tx * 4;
        acc0 = a.bsum[((c0    ) >> 4) * HH + jb * 16 + ((c0    ) & 15)];
        acc1 = a.bsum[((c0 + 1) >> 4) * HH + jb * 16 + ((c0 + 1) & 15)];
        acc2 = a.bsum[((c0 + 2) >> 4) * HH + jb * 16 + ((c0 + 2) & 15)];
        acc3 = a.bsum[((c0 + 3) >> 4) * HH + jb * 16 + ((c0 + 3) & 15)];
      }
      for (int kc = 0; kc < KK; kc += 32) {
        __syncthreads();
        {
          int r = t >> 4, c = (t & 15) * 2;
          const double* asrc = (kc < EE)
              ? (a.start + (size_t)(b0 + r) * EE + kc + c)
              : (hPrev   + (size_t)(b0 + r) * HH + (kc - EE) + c);
          *(double2*)&aS[r][c] = *(const double2*)asrc;
          int c4 = (t & 15) * 4;
          float4 bv = *(const float4*)&a.Wc[(size_t)(kc + r) * G4 + jb * 64 + c4];
          bS[r][c4]     = (double)bv.x;
          bS[r][c4 + 1] = (double)bv.y;
          bS[r][c4 + 2] = (double)bv.z;
          bS[r][c4 + 3] = (double)bv.w;
        }
        __syncthreads();
#pragma unroll 8
        for (int kk = 0; kk < 32; kk++) {
          double av = aS[ty][kk];
          double2 b01 = *(const double2*)&bS[kk][tx * 4];
          double2 b23 = *(const double2*)&bS[kk][tx * 4 + 2];
          acc0 += av * b01.x;
          acc1 += av * b01.y;
          acc2 += av * b23.x;
          acc3 += av * b23.y;
        }
      }
      __syncthreads();
      double (*gS)[66] = (double(*)[66])SMRAW;  // 32x66x8 = 16896 (overlays aS/bS)
      gS[ty][tx * 4]     = acc0;
      gS[ty][tx * 4 + 1] = acc1;
      gS[ty][tx * 4 + 2] = acc2;
      gS[ty][tx * 4 + 3] = acc3;
      __syncthreads();
      {
        const int b = t >> 4, w = t & 15;
        double ig = gS[b][w], fg = gS[b][16 + w], gv = gS[b][32 + w], og = gS[b][48 + w];
        double si = 1.0 / (1.0 + exp(-ig));
        double sf = 1.0 / (1.0 + exp(-fg));
        double so = 1.0 / (1.0 + exp(-og));
        size_t ci = (size_t)(b0 + b) * HH + jb * 16 + w;
        double cn = sf * a.c[ci] + si * tanh(gv);
        a.c[ci] = cn;
        hCur[ci] = so * tanh(cn);
      }
    }
    grid_barrier(bcnt, bgen);

    // ===== P2+P3 fused: block = batch b. q-MV in LDS, then attention+sample =====
    {
      double* hS  = (double*)SMRAW;            // 512*8 = 4096
      double* qS  = (double*)(SMRAW + 4096);   // 512*8 = 4096
      float*  vSf = (float*)(SMRAW + 8192);    // 512*4 = 2048
      double* red = (double*)(SMRAW + 10240);  // 512*8 = 4096
      double* sS  = (double*)(SMRAW + 14336);  // 256*8 = 2048
      int*   redi = (int*)(SMRAW + 16384);     // 256*4 = 1024
      int*   idxS = (int*)(SMRAW + 17408);
      const int b = blk;
      const int n = t & 255, half = t >> 8;
      hS[t] = hCur[(size_t)b * HH + t];
      vSf[t] = a.v[t];
      __syncthreads();

      // q[j=t] = sum_k h[k] * WqT[k][j]   (fp64, 4 interleaved partials)
      {
        const float* wp = a.WqT + t;
        double p0 = 0.0, p1 = 0.0, p2 = 0.0, p3 = 0.0;
        for (int k = 0; k < HH; k += 4) {
          p0 += hS[k]     * (double)wp[(size_t)k * HH];
          p1 += hS[k + 1] * (double)wp[(size_t)(k + 1) * HH];
          p2 += hS[k + 2] * (double)wp[(size_t)(k + 2) * HH];
          p3 += hS[k + 3] * (double)wp[(size_t)(k + 3) * HH];
        }
        qS[t] = (p0 + p1) + (p2 + p3);
      }
      __syncthreads();

      // scores: coalesced over n, half of h per thread-group
      const float* kp = a.kT + ((size_t)b * HH + half * 256) * NN + n;
      double a0 = 0.0, a1 = 0.0;
#pragma unroll 4
      for (int h = 0; h < 256; h += 2) {
        float k0 = kp[(size_t)h * NN];
        float k1 = kp[(size_t)(h + 1) * NN];
        int hh = half * 256 + h;
        a0 += (double)vSf[hh]     * (double)tanhf((float)(qS[hh]     + (double)k0));
        a1 += (double)vSf[hh + 1] * (double)tanhf((float)(qS[hh + 1] + (double)k1));
      }
      red[t] = a0 + a1;
      __syncthreads();

      if (t < 256) {
        double s = red[t] + red[256 + t];
        if (visS[t]) s -= 1.0e6;
        sS[t] = s;
      }
      __syncthreads();

      // gumbel: jax_threefry_partitionable=True categorical
      if (t < 256) {
        u32 fl = (u32)(b * 256 + t);
        u32 o0, o1;
        threefry2x32(a.keys[2 * step], a.keys[2 * step + 1], 0u, fl, o0, o1);
        u32 bits = o0 ^ o1;
        u32 fb = (bits >> 9) | 0x3F800000u;
        float uf = __uint_as_float(fb) - 1.0f;
        double u = (uf > 0.0f) ? (double)uf : (double)1.17549435e-38f;
        double gmb = -log(-log(u));
        red[t] = gmb + sS[t];
        redi[t] = t;
      }
      __syncthreads();
      for (int s2 = 128; s2 > 0; s2 >>= 1) {
        if (t < s2) {
          double v1 = red[t], v2 = red[t + s2];
          int i1 = redi[t], i2 = redi[t + s2];
          if (v2 > v1 || (v2 == v1 && i2 < i1)) { red[t] = v2; redi[t] = i2; }
        }
        __syncthreads();
      }
      if (t == 0) *idxS = redi[0];

      if (t < 256) red[t] = sS[t];
      __syncthreads();
      for (int s2 = 128; s2 > 0; s2 >>= 1) {
        if (t < s2) red[t] = fmax(red[t], red[t + s2]);
        __syncthreads();
      }
      double m = red[0];
      __syncthreads();
      if (t < 256) red[t] = exp(sS[t] - m);
      __syncthreads();
      for (int s2 = 128; s2 > 0; s2 >>= 1) {
        if (t < s2) red[t] += red[t + s2];
        __syncthreads();
      }
      if (t == 0) {
        int bi = *idxS;
        double p = exp(sS[bi] - m) / red[0];
        logpS += p;
        a.out[(size_t)b * TT + step] = (float)bi;
        visS[bi] = 1;
      }
      __syncthreads();
      if (t < 256) a.start[(size_t)b * EE + t] = (double)a.enc[((size_t)b * NN + *idxS) * EE + t];
    }
    grid_barrier(bcnt, bgen);
  }

  if (t == 0) a.out[BB * TT + blk] = (float)logpS;
}

// ---------------- host launch ---------------------------------------------
extern "C" void kernel_launch(void* const* d_in, const int* in_sizes, int n_in,
                              void* d_out, int out_size, void* d_ws, size_t ws_size,
                              hipStream_t stream) {
  char* ws = (char*)d_ws;
  Args a;
  a.enc  = (const float*)d_in[0];
  a.W_ih = (const float*)d_in[1];
  a.W_hh = (const float*)d_in[2];
  a.b_ih = (const float*)d_in[3];
  a.b_hh = (const float*)d_in[4];
  a.W_q  = (const float*)d_in[5];
  a.W_k  = (const float*)d_in[6];
  a.v    = (const float*)d_in[7];
  a.out  = (float*)d_out;

  a.kT    = (float*)(ws + 0);            // 134217728
  a.Wc    = (float*)(ws + 134217728);    // 6291456
  a.WqT   = (float*)(ws + 140509184);    // 1048576
  a.bsum  = (double*)(ws + 141557760);   // 16384
  a.keys  = (u32*)(ws + 141574144);      // 2048
  a.start = (double*)(ws + 141576192);   // 524288
  a.h0    = (double*)(ws + 142100480);   // 1048576
  a.h1    = (double*)(ws + 143149056);   // 1048576
  a.c     = (double*)(ws + 144197632);   // 1048576
  a.bar   = (u32*)(ws + 145246208);      // 256

  hipMemsetAsync((void*)a.bar, 0, 256, stream);

  void* kargs[] = { &a };
  hipLaunchCooperativeKernel(reinterpret_cast<void*>(&mono_kernel),
                             dim3(NBLK), dim3(NTHR), kargs, 0, stream);
}

// Round 5
// 42743.564 us; speedup vs baseline: 2.7844x; 1.7123x over previous
//
#include <hip/hip_runtime.h>
#include <cstdint>
#include <math.h>

typedef unsigned int u32;

#define BB 256   // batch
#define NN 256   // nodes
#define EE 256   // enc dim
#define HH 512   // hidden
#define G4 2048  // 4H
#define KK 768   // E + H
#define TT 256   // steps
#define NBLK 256
#define NTHR 512

// ---------------- Threefry-2x32, exactly as jax/_src/prng.py ----------------
__device__ __forceinline__ u32 rotl(u32 x, int d) { return (x << d) | (x >> (32 - d)); }

__device__ __forceinline__ void tf4(u32& x0, u32& x1, int r0, int r1, int r2, int r3) {
  x0 += x1; x1 = rotl(x1, r0); x1 ^= x0;
  x0 += x1; x1 = rotl(x1, r1); x1 ^= x0;
  x0 += x1; x1 = rotl(x1, r2); x1 ^= x0;
  x0 += x1; x1 = rotl(x1, r3); x1 ^= x0;
}

__device__ __forceinline__ void threefry2x32(u32 k0, u32 k1, u32 x0, u32 x1, u32& o0, u32& o1) {
  u32 k2 = k0 ^ k1 ^ 0x1BD11BDAu;
  x0 += k0; x1 += k1;
  tf4(x0, x1, 13, 15, 26, 6);  x0 += k1; x1 += k2 + 1u;
  tf4(x0, x1, 17, 29, 16, 24); x0 += k2; x1 += k0 + 2u;
  tf4(x0, x1, 13, 15, 26, 6);  x0 += k0; x1 += k1 + 3u;
  tf4(x0, x1, 17, 29, 16, 24); x0 += k1; x1 += k2 + 4u;
  tf4(x0, x1, 13, 15, 26, 6);  x0 += k2; x1 += k0 + 5u;
  o0 = x0; o1 = x1;
}

struct Args {
  const float *enc, *W_ih, *W_hh, *b_ih, *b_hh, *W_q, *W_k, *v;
  float *out;
  float *kT;       // [B][H][N] f32
  float *Wc;       // [K=768][2048] f32, gate-interleaved permuted columns
  float *WqT;      // [H][H] f32 (k-major)
  double *bsum;    // [2048]
  u32 *keys;       // [256][2]
  double *start;   // [B][E]
  double *h0, *h1; // [B][H] double-buffered hidden
  double *c;       // [B][H]
  u32 *flags;      // [g*32] p1done g=0..7 | [256+g*32] p2done | [512] cnt | [544] gen
};

// Full grid barrier (phase 0 only) — r4-proven pattern.
__device__ __forceinline__ void grid_barrier(u32* cnt, u32* gen) {
  __syncthreads();
  if (threadIdx.x == 0) {
    u32 g = __hip_atomic_load(gen, __ATOMIC_RELAXED, __HIP_MEMORY_SCOPE_AGENT);
    __threadfence();
    if (atomicAdd(cnt, 1u) == NBLK - 1u) {
      __hip_atomic_store(cnt, 0u, __ATOMIC_RELAXED, __HIP_MEMORY_SCOPE_AGENT);
      __threadfence();
      atomicAdd(gen, 1u);
    } else {
      while (__hip_atomic_load(gen, __ATOMIC_RELAXED, __HIP_MEMORY_SCOPE_AGENT) == g) {
        __builtin_amdgcn_s_sleep(2);
      }
    }
    __threadfence();
  }
  __syncthreads();
}

// Group handoff: signal = release + monotonic count; wait = poll then acquire.
__device__ __forceinline__ void group_signal(u32* flag) {
  __syncthreads();
  if (threadIdx.x == 0) {
    __threadfence();
    atomicAdd(flag, 1u);
  }
}
__device__ __forceinline__ void group_wait(u32* flag, u32 target) {
  if (threadIdx.x == 0) {
    while (__hip_atomic_load(flag, __ATOMIC_RELAXED, __HIP_MEMORY_SCOPE_AGENT) < target) {
      __builtin_amdgcn_s_sleep(1);
    }
    __threadfence();
  }
  __syncthreads();
}

__global__ __launch_bounds__(NTHR) void mono_kernel(Args a) {
  const int blk = blockIdx.x;
  const int t = threadIdx.x;
  __shared__ alignas(16) unsigned char SMRAW[33344];
  __shared__ int visS[NN];       // persistent per-block (batch = blk)
  __shared__ float vSp[HH];      // persistent copy of v
  __shared__ double logpS;
  const int grp = blk >> 5;      // batch group / producer group
  u32* p1done = a.flags + grp * 32;
  u32* p2done = a.flags + 256 + grp * 32;

  // ============ phase 0: init + weights + kenc ============
  {
    const int tid = blk * NTHR + t;
    const int tot = NBLK * NTHR;  // 131072
    if (tid < BB * EE) a.start[tid] = 0.0;
    if (tid < BB * HH) { a.h0[tid] = 0.0; a.c[tid] = 0.0; }
    if (tid < 256) {
      // jax_threefry_partitionable=True: split(key(42),256)
      u32 o0, o1;
      threefry2x32(0u, 42u, 0u, (u32)tid, o0, o1);
      a.keys[2 * tid] = o0; a.keys[2 * tid + 1] = o1;
    }
    if (tid < G4) a.bsum[tid] = (double)a.b_ih[tid] + (double)a.b_hh[tid];
    for (int i = tid; i < HH * HH; i += tot) {
      int h2 = i >> 9, h = i & 511;
      a.WqT[i] = a.W_q[h * HH + h2];
    }
    // Wc permuted: col = x16*64 + g*16 + w  <->  orig gate col j = g*512 + x16*16 + w
    for (int i = tid; i < KK * G4; i += tot) {
      int k = i >> 11, col = i & 2047;
      int x16 = col >> 6, g = (col >> 4) & 3, w = col & 15;
      int j = g * HH + x16 * 16 + w;
      a.Wc[i] = (k < EE) ? a.W_ih[j * EE + k] : a.W_hh[j * HH + (k - EE)];
    }
    if (t < NN) visS[t] = 0;
    vSp[t] = a.v[t];
    if (t == 0) logpS = 0.0;
  }
  // kenc: kT[b][h][n] = sum_e enc[b][n][e] * W_k[h][e], fp64 acc (e ascending)
  {
    float (*encS)[65] = (float(*)[65])SMRAW;
    float (*wkS)[65]  = (float(*)[65])(SMRAW + 64 * 65 * 4);
    const int tn = t & 63, th = t >> 6;  // th = wave id, 0..7
    for (int tile = blk; tile < 8 * 4 * BB; tile += NBLK) {
      const int bx = tile & 7, by = (tile >> 3) & 3, b = tile >> 5;
      const int h0i = bx * 64, n0 = by * 64;
      double acc[8];
#pragma unroll
      for (int i = 0; i < 8; i++) acc[i] = 0.0;
      for (int ec = 0; ec < EE; ec += 64) {
        __syncthreads();
#pragma unroll
        for (int i = 0; i < 8; i++) {
          int idx = i * NTHR + t; int r = idx >> 6, cc = idx & 63;
          encS[r][cc] = a.enc[((size_t)b * NN + n0 + r) * EE + ec + cc];
          wkS[r][cc]  = a.W_k[(size_t)(h0i + r) * EE + ec + cc];
        }
        __syncthreads();
#pragma unroll 8
        for (int e = 0; e < 64; e++) {
          double ev = (double)encS[tn][e];
#pragma unroll
          for (int i = 0; i < 8; i++) acc[i] += (double)wkS[th * 8 + i][e] * ev;
        }
      }
#pragma unroll
      for (int i = 0; i < 8; i++)
        a.kT[((size_t)b * HH + h0i + th * 8 + i) * NN + n0 + tn] = (float)acc[i];
    }
  }
  grid_barrier(a.flags + 512, a.flags + 544);

  // ============ decode loop ============
  for (int step = 0; step < TT; step++) {
    double* hPrev = (step & 1) ? a.h1 : a.h0;
    double* hCur  = (step & 1) ? a.h0 : a.h1;

    // wait for my group's consumers to have produced start(step-1)
    if (step > 0) group_wait(p2done, 32u * (u32)step);

    // ===== P1: gates GEMM (fp64) fused with LSTM; block = (jb, bt=grp) =====
    {
      double (*aS)[34] = (double(*)[34])SMRAW;            // 32x34x8 = 8704
      double (*bS)[68] = (double(*)[68])(SMRAW + 8704);   // 32x68x8 = 17408
      const int tx = t & 15, ty = t >> 4;   // ty 0..31 (row), tx*4 col quad
      const int jb = blk & 31;
      const int b0 = grp * 32;
      double acc0, acc1, acc2, acc3;
      {
        int c0 = tx * 4;
        acc0 = a.bsum[((c0    ) >> 4) * HH + jb * 16 + ((c0    ) & 15)];
        acc1 = a.bsum[((c0 + 1) >> 4) * HH + jb * 16 + ((c0 + 1) & 15)];
        acc2 = a.bsum[((c0 + 2) >> 4) * HH + jb * 16 + ((c0 + 2) & 15)];
        acc3 = a.bsum[((c0 + 3) >> 4) * HH + jb * 16 + ((c0 + 3) & 15)];
      }
      for (int kc = 0; kc < KK; kc += 32) {
        __syncthreads();
        {
          int r = t >> 4, c = (t & 15) * 2;
          const double* asrc = (kc < EE)
              ? (a.start + (size_t)(b0 + r) * EE + kc + c)
              : (hPrev   + (size_t)(b0 + r) * HH + (kc - EE) + c);
          *(double2*)&aS[r][c] = *(const double2*)asrc;
          int c4 = (t & 15) * 4;
          float4 bv = *(const float4*)&a.Wc[(size_t)(kc + r) * G4 + jb * 64 + c4];
          double2 d01; d01.x = (double)bv.x; d01.y = (double)bv.y;
          double2 d23; d23.x = (double)bv.z; d23.y = (double)bv.w;
          *(double2*)&bS[r][c4]     = d01;
          *(double2*)&bS[r][c4 + 2] = d23;
        }
        __syncthreads();
#pragma unroll 8
        for (int kk = 0; kk < 32; kk++) {
          double av = aS[ty][kk];
          double2 b01 = *(const double2*)&bS[kk][tx * 4];
          double2 b23 = *(const double2*)&bS[kk][tx * 4 + 2];
          acc0 += av * b01.x;
          acc1 += av * b01.y;
          acc2 += av * b23.x;
          acc3 += av * b23.y;
        }
      }
      __syncthreads();
      double (*gS)[66] = (double(*)[66])SMRAW;  // 32x66x8 = 16896 (overlays aS/bS)
      gS[ty][tx * 4]     = acc0;
      gS[ty][tx * 4 + 1] = acc1;
      gS[ty][tx * 4 + 2] = acc2;
      gS[ty][tx * 4 + 3] = acc3;
      __syncthreads();
      {
        const int b = t >> 4, w = t & 15;
        double ig = gS[b][w], fg = gS[b][16 + w], gv = gS[b][32 + w], og = gS[b][48 + w];
        double si = 1.0 / (1.0 + exp(-ig));
        double sf = 1.0 / (1.0 + exp(-fg));
        double so = 1.0 / (1.0 + exp(-og));
        size_t ci = (size_t)(b0 + b) * HH + jb * 16 + w;
        double cn = sf * a.c[ci] + si * tanh(gv);
        a.c[ci] = cn;
        hCur[ci] = so * tanh(cn);
      }
    }
    group_signal(p1done);

    // wait for all 32 producers of my batch's h
    group_wait(p1done, 32u * (u32)(step + 1));

    // ===== P2+P3: block = batch b. q-MV in LDS, then attention+sample =====
    {
      double* hS  = (double*)SMRAW;            // 512*8 = 4096
      double* qS  = (double*)(SMRAW + 4096);   // 512*8 = 4096
      double* red = (double*)(SMRAW + 8192);   // 512*8 = 4096
      double* sS  = (double*)(SMRAW + 12288);  // 256*8 = 2048
      int*   redi = (int*)(SMRAW + 14336);     // 256*4 = 1024
      int*   idxS = (int*)(SMRAW + 15360);
      const int b = blk;
      const int n = t & 255, half = t >> 8;
      hS[t] = hCur[(size_t)b * HH + t];
      __syncthreads();

      // q[j=t] = sum_k h[k] * WqT[k][j]   (fp64, 4 interleaved partials)
      {
        const float* wp = a.WqT + t;
        double p0 = 0.0, p1 = 0.0, p2 = 0.0, p3 = 0.0;
        for (int k = 0; k < HH; k += 4) {
          p0 += hS[k]     * (double)wp[(size_t)k * HH];
          p1 += hS[k + 1] * (double)wp[(size_t)(k + 1) * HH];
          p2 += hS[k + 2] * (double)wp[(size_t)(k + 2) * HH];
          p3 += hS[k + 3] * (double)wp[(size_t)(k + 3) * HH];
        }
        qS[t] = (p0 + p1) + (p2 + p3);
      }
      __syncthreads();

      // scores: coalesced over n, half of h per thread-group
      const float* kp = a.kT + ((size_t)b * HH + half * 256) * NN + n;
      double a0 = 0.0, a1 = 0.0;
#pragma unroll 8
      for (int h = 0; h < 256; h += 2) {
        float k0 = kp[(size_t)h * NN];
        float k1 = kp[(size_t)(h + 1) * NN];
        int hh = half * 256 + h;
        a0 += (double)vSp[hh]     * (double)tanhf((float)(qS[hh]     + (double)k0));
        a1 += (double)vSp[hh + 1] * (double)tanhf((float)(qS[hh + 1] + (double)k1));
      }
      red[t] = a0 + a1;
      __syncthreads();

      if (t < 256) {
        double s = red[t] + red[256 + t];
        if (visS[t]) s -= 1.0e6;
        sS[t] = s;
      }
      __syncthreads();

      // gumbel: jax_threefry_partitionable=True categorical
      if (t < 256) {
        u32 fl = (u32)(b * 256 + t);
        u32 o0, o1;
        threefry2x32(a.keys[2 * step], a.keys[2 * step + 1], 0u, fl, o0, o1);
        u32 bits = o0 ^ o1;
        u32 fb = (bits >> 9) | 0x3F800000u;
        float uf = __uint_as_float(fb) - 1.0f;
        double u = (uf > 0.0f) ? (double)uf : (double)1.17549435e-38f;
        double gmb = -log(-log(u));
        red[t] = gmb + sS[t];
        redi[t] = t;
      }
      __syncthreads();
      for (int s2 = 128; s2 > 0; s2 >>= 1) {
        if (t < s2) {
          double v1 = red[t], v2 = red[t + s2];
          int i1 = redi[t], i2 = redi[t + s2];
          if (v2 > v1 || (v2 == v1 && i2 < i1)) { red[t] = v2; redi[t] = i2; }
        }
        __syncthreads();
      }
      if (t == 0) *idxS = redi[0];

      if (t < 256) red[t] = sS[t];
      __syncthreads();
      for (int s2 = 128; s2 > 0; s2 >>= 1) {
        if (t < s2) red[t] = fmax(red[t], red[t + s2]);
        __syncthreads();
      }
      double m = red[0];
      __syncthreads();
      if (t < 256) red[t] = exp(sS[t] - m);
      __syncthreads();
      for (int s2 = 128; s2 > 0; s2 >>= 1) {
        if (t < s2) red[t] += red[t + s2];
        __syncthreads();
      }
      if (t == 0) {
        int bi = *idxS;
        double p = exp(sS[bi] - m) / red[0];
        logpS += p;
        a.out[(size_t)b * TT + step] = (float)bi;
        visS[bi] = 1;
      }
      __syncthreads();
      if (t < 256) a.start[(size_t)b * EE + t] = (double)a.enc[((size_t)b * NN + *idxS) * EE + t];
    }
    group_signal(p2done);
  }

  if (t == 0) a.out[BB * TT + blk] = (float)logpS;
}

// ---------------- host launch ---------------------------------------------
extern "C" void kernel_launch(void* const* d_in, const int* in_sizes, int n_in,
                              void* d_out, int out_size, void* d_ws, size_t ws_size,
                              hipStream_t stream) {
  char* ws = (char*)d_ws;
  Args a;
  a.enc  = (const float*)d_in[0];
  a.W_ih = (const float*)d_in[1];
  a.W_hh = (const float*)d_in[2];
  a.b_ih = (const float*)d_in[3];
  a.b_hh = (const float*)d_in[4];
  a.W_q  = (const float*)d_in[5];
  a.W_k  = (const float*)d_in[6];
  a.v    = (const float*)d_in[7];
  a.out  = (float*)d_out;

  a.kT    = (float*)(ws + 0);            // 134217728
  a.Wc    = (float*)(ws + 134217728);    // 6291456
  a.WqT   = (float*)(ws + 140509184);    // 1048576
  a.bsum  = (double*)(ws + 141557760);   // 16384
  a.keys  = (u32*)(ws + 141574144);      // 2048
  a.start = (double*)(ws + 141576192);   // 524288
  a.h0    = (double*)(ws + 142100480);   // 1048576
  a.h1    = (double*)(ws + 143149056);   // 1048576
  a.c     = (double*)(ws + 144197632);   // 1048576
  a.flags = (u32*)(ws + 145246208);      // 4096

  hipMemsetAsync((void*)a.flags, 0, 4096, stream);

  void* kargs[] = { &a };
  hipLaunchCooperativeKernel(reinterpret_cast<void*>(&mono_kernel),
                             dim3(NBLK), dim3(NTHR), kargs, 0, stream);
}

// Round 6
// 40388.885 us; speedup vs baseline: 2.9467x; 1.0583x over previous
//
#include <hip/hip_runtime.h>
#include <cstdint>
#include <math.h>

typedef unsigned int u32;

#define BB 256   // batch
#define NN 256   // nodes
#define EE 256   // enc dim
#define HH 512   // hidden
#define G4 2048  // 4H
#define KK 768   // E + H
#define TT 256   // steps
#define NBLK 256
#define NTHR 512

#define ALOADD(p)    __hip_atomic_load((p), __ATOMIC_RELAXED, __HIP_MEMORY_SCOPE_AGENT)
#define ASTORED(p,v) __hip_atomic_store((p), (v), __ATOMIC_RELAXED, __HIP_MEMORY_SCOPE_AGENT)
#define ALOADI(p)    __hip_atomic_load((p), __ATOMIC_RELAXED, __HIP_MEMORY_SCOPE_AGENT)
#define ASTOREI(p,v) __hip_atomic_store((p), (v), __ATOMIC_RELAXED, __HIP_MEMORY_SCOPE_AGENT)

// ---------------- Threefry-2x32, exactly as jax/_src/prng.py ----------------
__device__ __forceinline__ u32 rotl(u32 x, int d) { return (x << d) | (x >> (32 - d)); }

__device__ __forceinline__ void tf4(u32& x0, u32& x1, int r0, int r1, int r2, int r3) {
  x0 += x1; x1 = rotl(x1, r0); x1 ^= x0;
  x0 += x1; x1 = rotl(x1, r1); x1 ^= x0;
  x0 += x1; x1 = rotl(x1, r2); x1 ^= x0;
  x0 += x1; x1 = rotl(x1, r3); x1 ^= x0;
}

__device__ __forceinline__ void threefry2x32(u32 k0, u32 k1, u32 x0, u32 x1, u32& o0, u32& o1) {
  u32 k2 = k0 ^ k1 ^ 0x1BD11BDAu;
  x0 += k0; x1 += k1;
  tf4(x0, x1, 13, 15, 26, 6);  x0 += k1; x1 += k2 + 1u;
  tf4(x0, x1, 17, 29, 16, 24); x0 += k2; x1 += k0 + 2u;
  tf4(x0, x1, 13, 15, 26, 6);  x0 += k0; x1 += k1 + 3u;
  tf4(x0, x1, 17, 29, 16, 24); x0 += k1; x1 += k2 + 4u;
  tf4(x0, x1, 13, 15, 26, 6);  x0 += k2; x1 += k0 + 5u;
  o0 = x0; o1 = x1;
}

struct Args {
  const float *enc, *W_ih, *W_hh, *b_ih, *b_hh, *W_q, *W_k, *v;
  float *out;
  float *kT;       // [B][H][N] f32
  float *Wc;       // [K=768][2048] f32, gate-interleaved permuted columns
  float *WqT;      // [H][H] f32 (k-major)
  double *bsum;    // [2048]
  u32 *keys;       // [256][2]
  double *h0, *h1; // [B][H] double-buffered hidden (LLC-coherent traffic)
  double *c;       // [B][H] (private per P1 block after init)
  int *idx;        // [B] last sampled index (LLC-coherent)
  u32 *flags;      // [g*32] p1done g=0..7 | [256+g*32] p2done | [512] cnt | [544] gen
};

// Full grid barrier with cache maintenance — used ONCE after phase 0.
__device__ __forceinline__ void grid_barrier(u32* cnt, u32* gen) {
  __syncthreads();
  if (threadIdx.x == 0) {
    u32 g = __hip_atomic_load(gen, __ATOMIC_RELAXED, __HIP_MEMORY_SCOPE_AGENT);
    __threadfence();
    if (atomicAdd(cnt, 1u) == NBLK - 1u) {
      __hip_atomic_store(cnt, 0u, __ATOMIC_RELAXED, __HIP_MEMORY_SCOPE_AGENT);
      __threadfence();
      atomicAdd(gen, 1u);
    } else {
      while (__hip_atomic_load(gen, __ATOMIC_RELAXED, __HIP_MEMORY_SCOPE_AGENT) == g) {
        __builtin_amdgcn_s_sleep(2);
      }
    }
    __threadfence();
  }
  __syncthreads();
}

// Lock-free pod handoff, NO cache-wide fences. All cross-block data moves via
// agent-scope atomics (LLC). vmcnt(0) drain (asm + __syncthreads' own drain)
// guarantees the atomic data ops retired at LLC before the flag bump.
__device__ __forceinline__ void pod_signal(u32* flag) {
  asm volatile("s_waitcnt vmcnt(0)" ::: "memory");
  __syncthreads();
  if (threadIdx.x == 0) atomicAdd(flag, 1u);   // relaxed, agent scope
}
__device__ __forceinline__ void pod_wait(u32* flag, u32 target) {
  if (threadIdx.x == 0) {
    while (__hip_atomic_load(flag, __ATOMIC_RELAXED, __HIP_MEMORY_SCOPE_AGENT) < target) {
      __builtin_amdgcn_s_sleep(1);
    }
  }
  __syncthreads();
}

__global__ __launch_bounds__(NTHR) void mono_kernel(Args a) {
  const int blk = blockIdx.x;
  const int t = threadIdx.x;
  __shared__ alignas(16) unsigned char SMRAW[33344];
  __shared__ int visS[NN];       // persistent per-block (batch = blk)
  __shared__ float vSp[HH];      // persistent copy of v
  __shared__ double logpS;
  const int grp = blk >> 5;      // batch pod (32 blocks, batches [32g,32g+32))
  u32* p1done = a.flags + grp * 32;
  u32* p2done = a.flags + 256 + grp * 32;

  // ============ phase 0: init + weights + kenc ============
  {
    const int tid = blk * NTHR + t;
    const int tot = NBLK * NTHR;  // 131072
    if (tid < BB * HH) { a.h0[tid] = 0.0; a.c[tid] = 0.0; }
    if (tid < BB) a.idx[tid] = -1;
    if (tid < 256) {
      // jax_threefry_partitionable=True: split(key(42),256)
      u32 o0, o1;
      threefry2x32(0u, 42u, 0u, (u32)tid, o0, o1);
      a.keys[2 * tid] = o0; a.keys[2 * tid + 1] = o1;
    }
    if (tid < G4) a.bsum[tid] = (double)a.b_ih[tid] + (double)a.b_hh[tid];
    for (int i = tid; i < HH * HH; i += tot) {
      int h2 = i >> 9, h = i & 511;
      a.WqT[i] = a.W_q[h * HH + h2];
    }
    // Wc permuted: col = x16*64 + g*16 + w  <->  orig gate col j = g*512 + x16*16 + w
    for (int i = tid; i < KK * G4; i += tot) {
      int k = i >> 11, col = i & 2047;
      int x16 = col >> 6, g = (col >> 4) & 3, w = col & 15;
      int j = g * HH + x16 * 16 + w;
      a.Wc[i] = (k < EE) ? a.W_ih[j * EE + k] : a.W_hh[j * HH + (k - EE)];
    }
    if (t < NN) visS[t] = 0;
    vSp[t] = a.v[t];
    if (t == 0) logpS = 0.0;
  }
  // kenc: kT[b][h][n] = sum_e enc[b][n][e] * W_k[h][e], fp64 acc (e ascending)
  {
    float (*encS)[65] = (float(*)[65])SMRAW;
    float (*wkS)[65]  = (float(*)[65])(SMRAW + 64 * 65 * 4);
    const int tn = t & 63, th = t >> 6;  // th = wave id, 0..7
    for (int tile = blk; tile < 8 * 4 * BB; tile += NBLK) {
      const int bx = tile & 7, by = (tile >> 3) & 3, b = tile >> 5;
      const int h0i = bx * 64, n0 = by * 64;
      double acc[8];
#pragma unroll
      for (int i = 0; i < 8; i++) acc[i] = 0.0;
      for (int ec = 0; ec < EE; ec += 64) {
        __syncthreads();
#pragma unroll
        for (int i = 0; i < 8; i++) {
          int idx = i * NTHR + t; int r = idx >> 6, cc = idx & 63;
          encS[r][cc] = a.enc[((size_t)b * NN + n0 + r) * EE + ec + cc];
          wkS[r][cc]  = a.W_k[(size_t)(h0i + r) * EE + ec + cc];
        }
        __syncthreads();
#pragma unroll 8
        for (int e = 0; e < 64; e++) {
          double ev = (double)encS[tn][e];
#pragma unroll
          for (int i = 0; i < 8; i++) acc[i] += (double)wkS[th * 8 + i][e] * ev;
        }
      }
#pragma unroll
      for (int i = 0; i < 8; i++)
        a.kT[((size_t)b * HH + h0i + th * 8 + i) * NN + n0 + tn] = (float)acc[i];
    }
  }
  grid_barrier(a.flags + 512, a.flags + 544);

  // ============ decode loop ============
  for (int step = 0; step < TT; step++) {
    double* hPrev = (step & 1) ? a.h1 : a.h0;
    double* hCur  = (step & 1) ? a.h0 : a.h1;

    // wait for my pod's consumers to finish step-1 (idx published)
    if (step > 0) pod_wait(p2done, 32u * (u32)step);

    // ===== P1: gates GEMM (fp64) fused with LSTM; block = (jb, pod=grp) =====
    {
      double (*aS)[34] = (double(*)[34])SMRAW;            // 32x34x8 = 8704
      double (*bS)[68] = (double(*)[68])(SMRAW + 8704);   // 32x68x8 = 17408
      int* idxP = (int*)(SMRAW + 26112);                  // 32x4
      const int tx = t & 15, ty = t >> 4;   // ty 0..31 (row), tx*4 col quad
      const int jb = blk & 31;
      const int b0 = grp * 32;
      const int r = ty, c2 = tx * 2, c4 = tx * 4;
      if (t < 32) idxP[t] = ALOADI(&a.idx[b0 + t]);
      __syncthreads();

      double acc0, acc1, acc2, acc3;
      {
        int c0 = tx * 4;
        acc0 = a.bsum[((c0    ) >> 4) * HH + jb * 16 + ((c0    ) & 15)];
        acc1 = a.bsum[((c0 + 1) >> 4) * HH + jb * 16 + ((c0 + 1) & 15)];
        acc2 = a.bsum[((c0 + 2) >> 4) * HH + jb * 16 + ((c0 + 2) & 15)];
        acc3 = a.bsum[((c0 + 3) >> 4) * HH + jb * 16 + ((c0 + 3) & 15)];
      }
      // prefetch kc=0
      double aR0, aR1; float4 bR;
      {
        int iv = idxP[r];
        if (iv >= 0) {
          const float* ep = &a.enc[((size_t)(b0 + r) * NN + iv) * EE + c2];
          aR0 = (double)ep[0]; aR1 = (double)ep[1];
        } else { aR0 = 0.0; aR1 = 0.0; }
        bR = *(const float4*)&a.Wc[(size_t)r * G4 + jb * 64 + c4];
      }
      for (int kc = 0; kc < KK; kc += 32) {
        // stage prefetched regs
        aS[r][c2] = aR0; aS[r][c2 + 1] = aR1;
        {
          double2 d01; d01.x = (double)bR.x; d01.y = (double)bR.y;
          double2 d23; d23.x = (double)bR.z; d23.y = (double)bR.w;
          *(double2*)&bS[r][c4]     = d01;
          *(double2*)&bS[r][c4 + 2] = d23;
        }
        // prefetch next kc (overlaps this kc's compute)
        int kn = kc + 32;
        if (kn < KK) {
          if (kn < EE) {
            int iv = idxP[r];
            if (iv >= 0) {
              const float* ep = &a.enc[((size_t)(b0 + r) * NN + iv) * EE + kn + c2];
              aR0 = (double)ep[0]; aR1 = (double)ep[1];
            } else { aR0 = 0.0; aR1 = 0.0; }
          } else {
            double* hp = &hPrev[(size_t)(b0 + r) * HH + (kn - EE) + c2];
            aR0 = ALOADD(hp); aR1 = ALOADD(hp + 1);
          }
          bR = *(const float4*)&a.Wc[(size_t)(kn + r) * G4 + jb * 64 + c4];
        }
        __syncthreads();
#pragma unroll 8
        for (int kk = 0; kk < 32; kk++) {
          double av = aS[ty][kk];
          double2 b01 = *(const double2*)&bS[kk][tx * 4];
          double2 b23 = *(const double2*)&bS[kk][tx * 4 + 2];
          acc0 += av * b01.x;
          acc1 += av * b01.y;
          acc2 += av * b23.x;
          acc3 += av * b23.y;
        }
        __syncthreads();
      }
      double (*gS)[66] = (double(*)[66])SMRAW;  // 32x66x8 = 16896 (overlays aS/bS)
      gS[ty][tx * 4]     = acc0;
      gS[ty][tx * 4 + 1] = acc1;
      gS[ty][tx * 4 + 2] = acc2;
      gS[ty][tx * 4 + 3] = acc3;
      __syncthreads();
      {
        const int b = t >> 4, w = t & 15;
        double ig = gS[b][w], fg = gS[b][16 + w], gv = gS[b][32 + w], og = gS[b][48 + w];
        double si = 1.0 / (1.0 + exp(-ig));
        double sf = 1.0 / (1.0 + exp(-fg));
        double so = 1.0 / (1.0 + exp(-og));
        size_t ci = (size_t)(b0 + b) * HH + jb * 16 + w;
        double cn = sf * a.c[ci] + si * tanh(gv);
        a.c[ci] = cn;                 // private: plain cached
        ASTORED(&hCur[ci], so * tanh(cn));  // cross-block: LLC
      }
    }
    pod_signal(p1done);

    // wait for all 32 producers of my batch's h
    pod_wait(p1done, 32u * (u32)(step + 1));

    // ===== P2+P3: block = batch b. q-MV in LDS, then attention+sample =====
    {
      double* hS  = (double*)SMRAW;            // 512*8 = 4096
      double* qS  = (double*)(SMRAW + 4096);   // 512*8 = 4096
      double* red = (double*)(SMRAW + 8192);   // 512*8 = 4096
      double* sS  = (double*)(SMRAW + 12288);  // 256*8 = 2048
      int*   redi = (int*)(SMRAW + 14336);     // 256*4 = 1024
      int*   idxS = (int*)(SMRAW + 15360);
      const int b = blk;
      const int n = t & 255, half = t >> 8;
      hS[t] = ALOADD(&hCur[(size_t)b * HH + t]);
      __syncthreads();

      // q[j=t] = sum_k h[k] * WqT[k][j]   (fp64, 4 interleaved partials)
      {
        const float* wp = a.WqT + t;
        double p0 = 0.0, p1 = 0.0, p2 = 0.0, p3 = 0.0;
        for (int k = 0; k < HH; k += 4) {
          p0 += hS[k]     * (double)wp[(size_t)k * HH];
          p1 += hS[k + 1] * (double)wp[(size_t)(k + 1) * HH];
          p2 += hS[k + 2] * (double)wp[(size_t)(k + 2) * HH];
          p3 += hS[k + 3] * (double)wp[(size_t)(k + 3) * HH];
        }
        qS[t] = (p0 + p1) + (p2 + p3);
      }
      __syncthreads();

      // scores: coalesced over n, half of h per thread-group
      const float* kp = a.kT + ((size_t)b * HH + half * 256) * NN + n;
      double a0 = 0.0, a1 = 0.0;
#pragma unroll 8
      for (int h = 0; h < 256; h += 2) {
        float k0 = kp[(size_t)h * NN];
        float k1 = kp[(size_t)(h + 1) * NN];
        int hh = half * 256 + h;
        a0 += (double)vSp[hh]     * (double)tanhf((float)(qS[hh]     + (double)k0));
        a1 += (double)vSp[hh + 1] * (double)tanhf((float)(qS[hh + 1] + (double)k1));
      }
      red[t] = a0 + a1;
      __syncthreads();

      if (t < 256) {
        double s = red[t] + red[256 + t];
        if (visS[t]) s -= 1.0e6;
        sS[t] = s;
      }
      __syncthreads();

      // gumbel: jax_threefry_partitionable=True categorical
      if (t < 256) {
        u32 fl = (u32)(b * 256 + t);
        u32 o0, o1;
        threefry2x32(a.keys[2 * step], a.keys[2 * step + 1], 0u, fl, o0, o1);
        u32 bits = o0 ^ o1;
        u32 fb = (bits >> 9) | 0x3F800000u;
        float uf = __uint_as_float(fb) - 1.0f;
        double u = (uf > 0.0f) ? (double)uf : (double)1.17549435e-38f;
        double gmb = -log(-log(u));
        red[t] = gmb + sS[t];
        redi[t] = t;
      }
      __syncthreads();
      for (int s2 = 128; s2 > 0; s2 >>= 1) {
        if (t < s2) {
          double v1 = red[t], v2 = red[t + s2];
          int i1 = redi[t], i2 = redi[t + s2];
          if (v2 > v1 || (v2 == v1 && i2 < i1)) { red[t] = v2; redi[t] = i2; }
        }
        __syncthreads();
      }
      if (t == 0) *idxS = redi[0];

      if (t < 256) red[t] = sS[t];
      __syncthreads();
      for (int s2 = 128; s2 > 0; s2 >>= 1) {
        if (t < s2) red[t] = fmax(red[t], red[t + s2]);
        __syncthreads();
      }
      double m = red[0];
      __syncthreads();
      if (t < 256) red[t] = exp(sS[t] - m);
      __syncthreads();
      for (int s2 = 128; s2 > 0; s2 >>= 1) {
        if (t < s2) red[t] += red[t + s2];
        __syncthreads();
      }
      if (t == 0) {
        int bi = *idxS;
        double p = exp(sS[bi] - m) / red[0];
        logpS += p;
        a.out[(size_t)b * TT + step] = (float)bi;
        visS[bi] = 1;
        ASTOREI(&a.idx[b], bi);   // publish sampled index (producers gather enc row)
      }
    }
    pod_signal(p2done);
  }

  if (t == 0) a.out[BB * TT + blk] = (float)logpS;
}

// ---------------- host launch ---------------------------------------------
extern "C" void kernel_launch(void* const* d_in, const int* in_sizes, int n_in,
                              void* d_out, int out_size, void* d_ws, size_t ws_size,
                              hipStream_t stream) {
  char* ws = (char*)d_ws;
  Args a;
  a.enc  = (const float*)d_in[0];
  a.W_ih = (const float*)d_in[1];
  a.W_hh = (const float*)d_in[2];
  a.b_ih = (const float*)d_in[3];
  a.b_hh = (const float*)d_in[4];
  a.W_q  = (const float*)d_in[5];
  a.W_k  = (const float*)d_in[6];
  a.v    = (const float*)d_in[7];
  a.out  = (float*)d_out;

  a.kT    = (float*)(ws + 0);            // 134217728
  a.Wc    = (float*)(ws + 134217728);    // 6291456
  a.WqT   = (float*)(ws + 140509184);    // 1048576
  a.bsum  = (double*)(ws + 141557760);   // 16384
  a.keys  = (u32*)(ws + 141574144);      // 2048
  a.h0    = (double*)(ws + 141576192);   // 1048576
  a.h1    = (double*)(ws + 142624768);   // 1048576
  a.c     = (double*)(ws + 143673344);   // 1048576
  a.idx   = (int*)(ws + 144721920);      // 1024
  a.flags = (u32*)(ws + 144723968);      // 4096

  hipMemsetAsync((void*)a.flags, 0, 4096, stream);

  void* kargs[] = { &a };
  hipLaunchCooperativeKernel(reinterpret_cast<void*>(&mono_kernel),
                             dim3(NBLK), dim3(NTHR), kargs, 0, stream);
}